// Round 1
// baseline (3710.654 us; speedup 1.0000x reference)
//
#include <hip/hip_runtime.h>
#include <cstdint>

// LSTM fused kernel for MI355X — round 3.
// Topology unchanged from round 2 (64 blocks x 1024 threads, weights int8 in
// VGPRs, h broadcast via global + s_load into SGPRs with 2048-slot rotation).
// Round-3 changes attack EXPOSED SERIAL LATENCY in the step loop:
//  - h-record s_load split into issue (loop top) / tied wait (later); the
//    fc of step t-1 is software-pipelined into the load-latency window, so
//    its ds_read drain and the h-load drain share ONE stall.
//  - x quant-block loads hoisted to loop top (uniform-address register loads,
//    issued ~600cy before use) -> no blocking s_waitcnt in the A->B region.
//  - both cross-lane reductions (fc 32-lane sum, h-quant 64-lane max) moved
//    from ds_swizzle chains (lgkm, ~30cy/hop) to DPP (VALU, ~4cy/hop).

#define B_  64
#define T_  2048
#define I_  32
#define H_  256
#define G4  1024
#define O_  32

typedef int v16i __attribute__((ext_vector_type(16)));
typedef int v4i  __attribute__((ext_vector_type(4)));
typedef unsigned int v4u __attribute__((ext_vector_type(4)));
typedef _Float16 h2_t __attribute__((ext_vector_type(2)));

#if __has_builtin(__builtin_amdgcn_sdot4)
__device__ __forceinline__ int dot4(int a, int b, int c) {
    return __builtin_amdgcn_sdot4(a, b, c, false);
}
#else
__device__ __forceinline__ int dot4(int a, int b, int c) {
    c += (int)(int8_t)(a)        * (int)(int8_t)(b);
    c += (int)(int8_t)(a >> 8)   * (int)(int8_t)(b >> 8);
    c += (int)(int8_t)(a >> 16)  * (int)(int8_t)(b >> 16);
    c += (int)(int8_t)(a >> 24)  * (int)(int8_t)(b >> 24);
    return c;
}
#endif

__device__ __forceinline__ float fdot2h(h2_t a, h2_t b, float c) {
#if __has_builtin(__builtin_amdgcn_fdot2)
    return __builtin_amdgcn_fdot2(a, b, c, false);
#else
    return c + (float)a[0] * (float)b[0] + (float)a[1] * (float)b[1];
#endif
}

// ---- DPP cross-lane reductions (VALU pipe, no lgkm traffic) ----
// max over all 64 lanes, result broadcast to every lane via readlane.
__device__ __forceinline__ float wave64_max_bcast(float v) {
    int t;
    t = __builtin_amdgcn_update_dpp(__float_as_int(v), __float_as_int(v), 0x111, 0xf, 0xf, false);
    v = fmaxf(v, __int_as_float(t));   // row_shr:1
    t = __builtin_amdgcn_update_dpp(__float_as_int(v), __float_as_int(v), 0x112, 0xf, 0xf, false);
    v = fmaxf(v, __int_as_float(t));   // row_shr:2
    t = __builtin_amdgcn_update_dpp(__float_as_int(v), __float_as_int(v), 0x114, 0xf, 0xf, false);
    v = fmaxf(v, __int_as_float(t));   // row_shr:4
    t = __builtin_amdgcn_update_dpp(__float_as_int(v), __float_as_int(v), 0x118, 0xf, 0xf, false);
    v = fmaxf(v, __int_as_float(t));   // row_shr:8  -> lane15/31/47/63 = row max
    t = __builtin_amdgcn_update_dpp(__float_as_int(v), __float_as_int(v), 0x142, 0xa, 0xf, false);
    v = fmaxf(v, __int_as_float(t));   // row_bcast:15 rows 1,3
    t = __builtin_amdgcn_update_dpp(__float_as_int(v), __float_as_int(v), 0x143, 0xc, 0xf, false);
    v = fmaxf(v, __int_as_float(t));   // row_bcast:31 rows 2,3 -> lane63 = max
    return __int_as_float(__builtin_amdgcn_readlane(__float_as_int(v), 63));
}

// sum within each 32-lane half; lane31 = sum(0..31), lane63 = sum(32..63).
__device__ __forceinline__ float halfwave_sum31(float v) {
    int t;
    t = __builtin_amdgcn_update_dpp(0, __float_as_int(v), 0x111, 0xf, 0xf, true); v += __int_as_float(t);
    t = __builtin_amdgcn_update_dpp(0, __float_as_int(v), 0x112, 0xf, 0xf, true); v += __int_as_float(t);
    t = __builtin_amdgcn_update_dpp(0, __float_as_int(v), 0x114, 0xf, 0xf, true); v += __int_as_float(t);
    t = __builtin_amdgcn_update_dpp(0, __float_as_int(v), 0x118, 0xf, 0xf, true); v += __int_as_float(t);
    t = __builtin_amdgcn_update_dpp(0, __float_as_int(v), 0x142, 0xa, 0xf, true); v += __int_as_float(t);
    return v;
}

// ---------------- ws layout (all 256-B aligned) ----------------
#define QWHH_OFF 0
#define QWIH_OFF 262144
#define S1_OFF   327680
#define S2_OFF   331776
#define BIAS_OFF 335872
#define XQ_OFF   339968
#define XS_OFF   8728576
#define HBUF_OFF 9252864
#define HREC_STRIDE 320
#define HSLOTS 2049

__device__ __forceinline__ uint32_t pack_q(int q0, int q1, int q2, int q3) {
    return  ((uint32_t)(uint8_t)(int8_t)q0)
          | (((uint32_t)(uint8_t)(int8_t)q1) << 8)
          | (((uint32_t)(uint8_t)(int8_t)q2) << 16)
          | (((uint32_t)(uint8_t)(int8_t)q3) << 24);
}

__device__ __forceinline__ int clamp127(int v) {
    return v < -127 ? -127 : (v > 127 ? 127 : v);
}

// -------- prep: quantize weights (1 block of 64 thr per gate-row) --------
__global__ __launch_bounds__(64) void prep_w(
    const float* __restrict__ Whh, const float* __restrict__ Wih,
    const float* __restrict__ bih, const float* __restrict__ bhh,
    uint32_t* __restrict__ qwhh, uint32_t* __restrict__ qwih,
    float* __restrict__ s1, float* __restrict__ s2, float* __restrict__ bias)
{
    const int r = blockIdx.x;
    const int l = threadIdx.x;

    const float4 wv = ((const float4*)(Whh + r * H_))[l];
    float m = fmaxf(fmaxf(fabsf(wv.x), fabsf(wv.y)), fmaxf(fabsf(wv.z), fabsf(wv.w)));
    #pragma unroll
    for (int s = 1; s < 64; s <<= 1) m = fmaxf(m, __shfl_xor(m, s, 64));
    const float S1 = fmaxf(m, 1e-20f) / 127.f;

    float xm = (l < I_) ? fabsf(Wih[r * I_ + l]) : 0.f;
    #pragma unroll
    for (int s = 1; s < 64; s <<= 1) xm = fmaxf(xm, __shfl_xor(xm, s, 64));
    const float S2 = fmaxf(xm, 1e-20f) / 127.f;

    {
        const float r1 = 1.f / S1;
        qwhh[l * G4 + r] = pack_q(
            clamp127((int)rintf(wv.x * r1)), clamp127((int)rintf(wv.y * r1)),
            clamp127((int)rintf(wv.z * r1)), clamp127((int)rintf(wv.w * r1)));
    }
    if (l < 8) {
        const float4 xw = ((const float4*)(Wih + r * I_))[l];
        const float r2 = 1.f / S2;
        qwih[l * G4 + r] = pack_q(
            clamp127((int)rintf(xw.x * r2)), clamp127((int)rintf(xw.y * r2)),
            clamp127((int)rintf(xw.z * r2)), clamp127((int)rintf(xw.w * r2)));
    } else if (l < 16) {
        const int j = l - 8;
        const float4 xw = ((const float4*)(Wih + r * I_))[j];
        const float r2 = 1.f / S2;
        float v0 = xw.x * r2, v1 = xw.y * r2, v2 = xw.z * r2, v3 = xw.w * r2;
        int a0 = clamp127((int)rintf(v0)), a1 = clamp127((int)rintf(v1));
        int a2 = clamp127((int)rintf(v2)), a3 = clamp127((int)rintf(v3));
        qwih[(8 + j) * G4 + r] = pack_q(
            clamp127((int)rintf((v0 - (float)a0) * 127.f)),
            clamp127((int)rintf((v1 - (float)a1) * 127.f)),
            clamp127((int)rintf((v2 - (float)a2) * 127.f)),
            clamp127((int)rintf((v3 - (float)a3) * 127.f)));
    }
    if (l == 0) { s1[r] = S1; s2[r] = S2; bias[r] = bih[r] + bhh[r]; }
}

// -------- prep: quantize x (64 (b,t) rows per block) --------
__global__ __launch_bounds__(256) void prep_x(
    const float* __restrict__ x, uint32_t* __restrict__ xq, float* __restrict__ xs)
{
    __shared__ float xb[64 * 32];
    const int base = blockIdx.x * 64 * 32;
    for (int i = threadIdx.x; i < 2048; i += 256) xb[i] = x[base + i];
    __syncthreads();
    const int t = threadIdx.x;
    if (t < 64) {
        float m = 0.f;
        for (int k = 0; k < 32; k++) m = fmaxf(m, fabsf(xb[t * 32 + k]));
        const float S = fmaxf(m, 1e-20f) / 127.f;
        const int row = blockIdx.x * 64 + t;
        xs[row] = S;
        const float rS = 1.f / S;
        for (int j = 0; j < 8; j++) {
            int qa[4], qb[4];
            for (int e = 0; e < 4; e++) {
                float v = xb[t * 32 + j * 4 + e] * rS;
                int a = clamp127((int)rintf(v));
                int b = clamp127((int)rintf((v - (float)a) * 127.f));
                qa[e] = a; qb[e] = b;
            }
            xq[row * 16 + j]     = pack_q(qa[0], qa[1], qa[2], qa[3]);
            xq[row * 16 + 8 + j] = pack_q(qb[0], qb[1], qb[2], qb[3]);
        }
    }
}

// x contribution from registers (hi/lo int8 split)
__device__ __forceinline__ float xdots(v4u x0, v4u x1, v4u x2, v4u x3, float sx,
                                       const uint32_t* wA, const uint32_t* wB,
                                       float S2, float bias_r) {
    int aA = 0, aM = 0;
    #pragma unroll
    for (int j = 0; j < 4; j++) {
        aA = dot4((int)wA[j],     (int)x0[j], aA);
        aM = dot4((int)wA[j],     (int)x2[j], aM);
        aM = dot4((int)wB[j],     (int)x0[j], aM);
        aA = dot4((int)wA[4 + j], (int)x1[j], aA);
        aM = dot4((int)wA[4 + j], (int)x3[j], aM);
        aM = dot4((int)wB[4 + j], (int)x1[j], aM);
    }
    return ((float)aA + (float)aM * (1.f / 127.f)) * (S2 * sx) + bias_r;
}

// -------- main: full LSTM + fc, one block per batch, 1024 threads --------
__global__ __launch_bounds__(1024, 4) void lstm_main(
    const uint32_t* __restrict__ qwhh, const uint32_t* __restrict__ qwih,
    const float* __restrict__ s1v, const float* __restrict__ s2v,
    const float* __restrict__ biasv,
    const uint32_t* __restrict__ xq, const float* __restrict__ xs,
    const float* __restrict__ fcw, const float* __restrict__ fcb,
    char* __restrict__ hbuf, float* __restrict__ out)
{
    const int b   = blockIdx.x;
    const int tid = threadIdx.x;

    __shared__ float    gbuf[768];   // f,g,o gate exchange
    __shared__ uint32_t hf16[128];   // h as f16 pairs (for fc)

    // resident int8 weights: row = tid
    uint32_t w[64], wA[8], wB[8];
    #pragma unroll
    for (int d = 0; d < 64; d++) w[d] = qwhh[d * G4 + tid];
    #pragma unroll
    for (int j = 0; j < 8; j++) { wA[j] = qwih[j * G4 + tid]; wB[j] = qwih[(8 + j) * G4 + tid]; }
    const float S1 = s1v[tid], S2 = s2v[tid], bias_r = biasv[tid];

    // fc weights f16 in regs: o_=tid>>5 (0..31), kc=tid&31 -> k in [8kc,8kc+8)
    const int o_ = tid >> 5, kc = tid & 31;
    h2_t fw[4];
    {
        const float* fr = fcw + o_ * H_ + kc * 8;
        #pragma unroll
        for (int j = 0; j < 4; j++) {
            h2_t p; p[0] = (_Float16)fr[2 * j]; p[1] = (_Float16)fr[2 * j + 1];
            fw[j] = p;
        }
    }
    const float fcb_v = fcb[o_];

    char* hb = hbuf + (size_t)b * (HSLOTS * HREC_STRIDE);
    // init slot 2048 = zero h state
    if (tid < H_) hb[2048 * HREC_STRIDE + tid] = 0;
    if (tid >= 256 && tid < 260) ((float*)(hb + 2048 * HREC_STRIDE + 256))[tid - 256] = 0.f;

    const uint32_t* xqb  = xq + (size_t)(b * T_) * 16;
    const float*    xsb  = xs + (size_t)(b * T_);
    float*          outb = out + (size_t)(b * T_) * O_;

    float c_state = 0.f;  // valid for tid < 256
    float x_part;
    {   // x contribution for t=0
        const v4u x0 = *(const v4u*)(xqb);     const v4u x1 = *(const v4u*)(xqb + 4);
        const v4u x2 = *(const v4u*)(xqb + 8); const v4u x3 = *(const v4u*)(xqb + 12);
        x_part = xdots(x0, x1, x2, x3, xsb[0], wA, wB, S2, bias_r);
    }

    __syncthreads();  // drain init stores (vmcnt flushed at barrier)

    for (int t = 0; t < T_; t++) {
        // --- issue h-record scalar loads, NO wait yet ---
        const uint32_t slot = (t == 0) ? 2048u : ((uint32_t)(t * 1993) & 2047u);
        const char* hrec = hb + (size_t)slot * HREC_STRIDE;
        v16i h0, h1, h2, h3; v4i scv;
        asm volatile("s_load_dwordx16 %0, %5, 0x0\n\t"
                     "s_load_dwordx16 %1, %5, 0x40\n\t"
                     "s_load_dwordx16 %2, %5, 0x80\n\t"
                     "s_load_dwordx16 %3, %5, 0xc0\n\t"
                     "s_load_dwordx4  %4, %5, 0x100"
                     : "=&s"(h0), "=&s"(h1), "=&s"(h2), "=&s"(h3), "=&s"(scv)
                     : "s"(hrec)
                     : "memory");

        // --- x quant block for t+1: uniform-address register loads,
        //     issued here, consumed after barrier A (latency fully hidden) ---
        const int tn = (t + 1 < T_) ? (t + 1) : t;
        const uint32_t* px = xqb + (size_t)tn * 16;
        const v4u x0 = *(const v4u*)(px);     const v4u x1 = *(const v4u*)(px + 4);
        const v4u x2 = *(const v4u*)(px + 8); const v4u x3 = *(const v4u*)(px + 12);
        const float sx = xsb[tn];

        // --- fc(t-1), pipelined into the h-load latency window ---
        if (t > 0) {
            const v4u hv = *(const v4u*)(&hf16[4 * kc]);  // ds_read; its drain
            union { uint32_t u; h2_t h; } u0, u1, u2, u3; // merges with h s_load
            u0.u = hv[0]; u1.u = hv[1]; u2.u = hv[2]; u3.u = hv[3];
            float acc = 0.f;
            acc = fdot2h(fw[0], u0.h, acc);
            acc = fdot2h(fw[1], u1.h, acc);
            acc = fdot2h(fw[2], u2.h, acc);
            acc = fdot2h(fw[3], u3.h, acc);
            acc = halfwave_sum31(acc);                    // DPP, VALU-only
            if ((tid & 31) == 31) outb[(t - 1) * O_ + o_] = acc + fcb_v;
        }

        // --- wait (tied to h regs so dots can't be hoisted above it) ---
        asm volatile("s_waitcnt lgkmcnt(0)"
                     : "+s"(h0), "+s"(h1), "+s"(h2), "+s"(h3), "+s"(scv)
                     :
                     : "memory");

        int a0 = 0, a1 = 0, a2 = 0, a3 = 0;
        #pragma unroll
        for (int d = 0; d < 16; d++) {
            a0 = dot4((int)w[d],      h0[d], a0);
            a1 = dot4((int)w[16 + d], h1[d], a1);
            a2 = dot4((int)w[32 + d], h2[d], a2);
            a3 = dot4((int)w[48 + d], h3[d], a3);
        }
        const float hsum = (float)a0 * __int_as_float(scv[0])
                         + (float)a1 * __int_as_float(scv[1])
                         + (float)a2 * __int_as_float(scv[2])
                         + (float)a3 * __int_as_float(scv[3]);
        const float gate = hsum * S1 + x_part;

        if (tid >= 256) gbuf[tid - 256] = gate;
        __syncthreads();                                   // A: gates published

        const uint32_t wslot = (uint32_t)((t + 1) * 1993) & 2047u;
        char* hw = hb + (size_t)wslot * HREC_STRIDE;
        if (tid < H_) {
            const float gi = gate;
            const float gf = gbuf[tid];
            const float gg = gbuf[256 + tid];
            const float go = gbuf[512 + tid];
            const float i_ = 1.f / (1.f + __expf(-gi));
            const float f_ = 1.f / (1.f + __expf(-gf));
            const float g_ = 2.f / (1.f + __expf(-2.f * gg)) - 1.f;
            const float oo = 1.f / (1.f + __expf(-go));
            c_state = f_ * c_state + i_ * g_;
            const float tc = 2.f / (1.f + __expf(-2.f * c_state)) - 1.f;
            const float hval = oo * tc;
            ((_Float16*)hf16)[tid] = (_Float16)hval;

            // per-wave (64-elem group) max via DPP + int8 quantize + publish
            float m = wave64_max_bcast(fabsf(hval));
            m = fmaxf(m, 1e-12f);
            const float rq = 127.f / m;
            const int q = clamp127((int)rintf(hval * rq));
            hw[tid] = (char)(int8_t)q;
            if ((tid & 63) == 0)
                ((float*)(hw + 256))[tid >> 6] = m * (1.f / 127.f);
        }

        // x contribution for t+1 (loads were issued at loop top)
        x_part = xdots(x0, x1, x2, x3, sx, wA, wB, S2, bias_r);

        __syncthreads();                                   // B: h(t+1), hf16 published
    }

    // epilogue: fc for the final timestep
    {
        const v4u hv = *(const v4u*)(&hf16[4 * kc]);
        union { uint32_t u; h2_t h; } u0, u1, u2, u3;
        u0.u = hv[0]; u1.u = hv[1]; u2.u = hv[2]; u3.u = hv[3];
        float acc = 0.f;
        acc = fdot2h(fw[0], u0.h, acc);
        acc = fdot2h(fw[1], u1.h, acc);
        acc = fdot2h(fw[2], u2.h, acc);
        acc = fdot2h(fw[3], u3.h, acc);
        acc = halfwave_sum31(acc);
        if ((tid & 31) == 31) outb[(T_ - 1) * O_ + o_] = acc + fcb_v;
    }
}

extern "C" void kernel_launch(void* const* d_in, const int* in_sizes, int n_in,
                              void* d_out, int out_size, void* d_ws, size_t ws_size,
                              hipStream_t stream) {
    const float* x    = (const float*)d_in[0];
    const float* Wih  = (const float*)d_in[1];
    const float* Whh  = (const float*)d_in[2];
    const float* bih  = (const float*)d_in[3];
    const float* bhh  = (const float*)d_in[4];
    const float* fcw  = (const float*)d_in[5];
    const float* fcb  = (const float*)d_in[6];
    float* out = (float*)d_out;

    char* ws = (char*)d_ws;
    uint32_t* qwhh = (uint32_t*)(ws + QWHH_OFF);
    uint32_t* qwih = (uint32_t*)(ws + QWIH_OFF);
    float*    s1   = (float*)(ws + S1_OFF);
    float*    s2   = (float*)(ws + S2_OFF);
    float*    bias = (float*)(ws + BIAS_OFF);
    uint32_t* xq   = (uint32_t*)(ws + XQ_OFF);
    float*    xs   = (float*)(ws + XS_OFF);
    char*     hbuf = ws + HBUF_OFF;

    prep_w<<<G4, 64, 0, stream>>>(Whh, Wih, bih, bhh, qwhh, qwih, s1, s2, bias);
    prep_x<<<(B_ * T_) / 64, 256, 0, stream>>>(x, xq, xs);
    lstm_main<<<B_, 1024, 0, stream>>>(qwhh, qwih, s1, s2, bias, xq, xs,
                                       fcw, fcb, hbuf, out);
}